// Round 23
// baseline (209.244 us; speedup 1.0000x reference)
//
#include <hip/hip_runtime.h>
#include <math.h>

#define NH 16
#define TT 1024
#define CC 1024
#define DD 64
#define MM 8192
#define MQ 5            // uneven M split: 4x1664 + 1x1536
#define MQB 1664

typedef __attribute__((ext_vector_type(8))) short short8;
typedef __attribute__((ext_vector_type(4))) float f32x4;

// ---------------- helpers ----------------
__device__ __forceinline__ float wredsum(float x) {
#pragma unroll
  for (int o = 32; o; o >>= 1) x += __shfl_xor(x, o);
  return x;
}
__device__ __forceinline__ unsigned int bf16rn(float x) {
  unsigned int u = __float_as_uint(x);
  return (u + 0x7fffu + ((u >> 16) & 1u)) >> 16;
}
__device__ __forceinline__ float bf16f(unsigned int h) {
  return __uint_as_float(h << 16);
}

__device__ __forceinline__ void ins4(float d, int i, float vd[4], int vi[4]) {
  if (d < vd[3] || (d == vd[3] && i < vi[3])) {
    vd[3] = d; vi[3] = i;
#pragma unroll
    for (int s = 3; s > 0; --s) {
      bool sw = (vd[s] < vd[s - 1]) || (vd[s] == vd[s - 1] && vi[s] < vi[s - 1]);
      if (sw) {
        float td = vd[s]; vd[s] = vd[s - 1]; vd[s - 1] = td;
        int ti = vi[s]; vi[s] = vi[s - 1]; vi[s - 1] = ti;
      }
    }
  }
}

// ---------------- staging (global LINEAR -> LDS swizzled) ----------------
__device__ __forceinline__ void stage_rows8_swz(const char* gRow0, size_t gStride, char* lds, int lane) {
  int rr = lane >> 3;
  int c = (lane & 7) ^ rr;
  __builtin_amdgcn_global_load_lds(
      (const __attribute__((address_space(1))) unsigned int*)(gRow0 + (size_t)rr * gStride + (c << 4)),
      (__attribute__((address_space(3))) unsigned int*)lds, 16, 0, 0);
}

// ---------------- fused converts ----------------
__device__ __forceinline__ void conv_chunk(const float* __restrict__ src,
                                           char* __restrict__ hi, char* __restrict__ lo, int gc) {
  const float* p = src + ((size_t)gc << 3);
  float4 f0 = *(const float4*)p;
  float4 f1 = *(const float4*)(p + 4);
  float f[8] = {f0.x, f0.y, f0.z, f0.w, f1.x, f1.y, f1.z, f1.w};
  short8 hv, lv;
#pragma unroll
  for (int e = 0; e < 8; ++e) {
    unsigned hb = bf16rn(f[e]);
    hv[e] = (short)hb;
    lv[e] = (short)bf16rn(f[e] - bf16f(hb));
  }
  size_t off = (size_t)gc << 4;
  *(short8*)(hi + off) = hv;
  *(short8*)(lo + off) = lv;
}

__device__ __forceinline__ void conv_chunk_hi(const float* __restrict__ src,
                                              char* __restrict__ hi, int gc) {
  const float* p = src + ((size_t)gc << 3);
  float4 f0 = *(const float4*)p;
  float4 f1 = *(const float4*)(p + 4);
  float f[8] = {f0.x, f0.y, f0.z, f0.w, f1.x, f1.y, f1.z, f1.w};
  short8 hv;
#pragma unroll
  for (int e = 0; e < 8; ++e) hv[e] = (short)bf16rn(f[e]);
  *(short8*)(hi + ((size_t)gc << 4)) = hv;
}

__global__ void __launch_bounds__(256) convert_all(
    const float* __restrict__ x, char* __restrict__ xhi, char* __restrict__ xlo,
    const float* __restrict__ Wa, char* __restrict__ wahi, char* __restrict__ walo,
    const float* __restrict__ Wp, char* __restrict__ wphi,
    const float* __restrict__ ks, char* __restrict__ khi, char* __restrict__ klo,
    float* __restrict__ kn2)
{
  int b = blockIdx.x, tid = threadIdx.x;
  if (b < 512) { conv_chunk(x, xhi, xlo, b * 256 + tid); return; }
  if (b < 2048) {
    int gc = (b - 512) * 256 + tid;
    if (gc < 262144) conv_chunk(Wa, wahi, walo, gc);       // q,k rows: hi+lo
    else conv_chunk_hi(Wa, wahi, gc);                      // v rows: hi only
    return;
  }
  if (b < 2560) { conv_chunk_hi(Wp, wphi, (b - 2048) * 256 + tid); return; }
  int gc = (b - 2560) * 256 + tid;
  const float* p = ks + ((size_t)gc << 3);
  float4 f0 = *(const float4*)p;
  float4 f1 = *(const float4*)(p + 4);
  float f[8] = {f0.x, f0.y, f0.z, f0.w, f1.x, f1.y, f1.z, f1.w};
  float s = 0.f;
  short8 hv, lv;
#pragma unroll
  for (int e = 0; e < 8; ++e) {
    s = fmaf(f[e], f[e], s);
    unsigned hb = bf16rn(f[e]);
    hv[e] = (short)hb;
    lv[e] = (short)bf16rn(f[e] - bf16f(hb));
  }
  size_t off = (size_t)gc << 4;
  *(short8*)(khi + off) = hv;
  *(short8*)(klo + off) = lv;
  s += __shfl_xor(s, 1);
  s += __shfl_xor(s, 2);
  s += __shfl_xor(s, 4);
  if ((tid & 7) == 0) kn2[gc >> 3] = -0.5f * s;
}

// ---------------- qkv = x @ Wa^T + ba -> linear HL (direct) ----------------
__global__ void __launch_bounds__(256) gemm_qkv(
    const char* __restrict__ xhi, const char* __restrict__ xlo,
    const char* __restrict__ wahi, const char* __restrict__ walo,
    const float* __restrict__ ba, char* __restrict__ qhi, char* __restrict__ qlo)
{
  int n0 = blockIdx.x * 128, m0 = blockIdx.y * 64;
  bool vsec = (n0 >= 2048);
  int tid = threadIdx.x, lane = tid & 63, w = tid >> 6;
  int wr = w >> 1, wc = w & 1;
  int lr = lane & 15, lc = lane >> 4;
  __shared__ __align__(16) char smem[49152];
  char* sAhi = smem;
  char* sAlo = smem + 8192;
  char* sBhi = smem + 16384;
  char* sBlo = smem + 32768;
  f32x4 acc[2][4];
#pragma unroll
  for (int i = 0; i < 2; ++i)
#pragma unroll
    for (int j = 0; j < 4; ++j) acc[i][j] = (f32x4){0.f, 0.f, 0.f, 0.f};

  for (int kb = 0; kb < 16; ++kb) {
    if (kb) __syncthreads();
#pragma unroll
    for (int c8 = 0; c8 < 2; ++c8) {
      int r8 = w * 16 + c8 * 8;
      stage_rows8_swz(xhi + (size_t)(m0 + r8) * 2048 + (size_t)kb * 128, 2048, sAhi + r8 * 128, lane);
      if (!vsec)
        stage_rows8_swz(xlo + (size_t)(m0 + r8) * 2048 + (size_t)kb * 128, 2048, sAlo + r8 * 128, lane);
    }
#pragma unroll
    for (int c8 = 0; c8 < 4; ++c8) {
      int r8 = w * 32 + c8 * 8;
      stage_rows8_swz(wahi + (size_t)(n0 + r8) * 2048 + (size_t)kb * 128, 2048, sBhi + r8 * 128, lane);
      if (!vsec)
        stage_rows8_swz(walo + (size_t)(n0 + r8) * 2048 + (size_t)kb * 128, 2048, sBlo + r8 * 128, lane);
    }
    __syncthreads();
#pragma unroll
    for (int kh = 0; kh < 2; ++kh) {
      short8 ah[2], al[2], bh[4], bl[4];
#pragma unroll
      for (int mi = 0; mi < 2; ++mi) {
        int ra = wr * 32 + mi * 16 + lr;
        int ca = ((kh * 4 + lc) ^ (ra & 7)) << 4;
        ah[mi] = *(const short8*)(sAhi + ra * 128 + ca);
        if (!vsec) al[mi] = *(const short8*)(sAlo + ra * 128 + ca);
      }
#pragma unroll
      for (int nj = 0; nj < 4; ++nj) {
        int rb = wc * 64 + nj * 16 + lr;
        int cb = ((kh * 4 + lc) ^ (rb & 7)) << 4;
        bh[nj] = *(const short8*)(sBhi + rb * 128 + cb);
        if (!vsec) bl[nj] = *(const short8*)(sBlo + rb * 128 + cb);
      }
      if (!vsec) {
#pragma unroll
        for (int mi = 0; mi < 2; ++mi)
#pragma unroll
          for (int nj = 0; nj < 4; ++nj) {
            acc[mi][nj] = __builtin_amdgcn_mfma_f32_16x16x32_bf16(ah[mi], bh[nj], acc[mi][nj], 0, 0, 0);
            acc[mi][nj] = __builtin_amdgcn_mfma_f32_16x16x32_bf16(al[mi], bh[nj], acc[mi][nj], 0, 0, 0);
            acc[mi][nj] = __builtin_amdgcn_mfma_f32_16x16x32_bf16(ah[mi], bl[nj], acc[mi][nj], 0, 0, 0);
          }
      } else {
#pragma unroll
        for (int mi = 0; mi < 2; ++mi)
#pragma unroll
          for (int nj = 0; nj < 4; ++nj)
            acc[mi][nj] = __builtin_amdgcn_mfma_f32_16x16x32_bf16(ah[mi], bh[nj], acc[mi][nj], 0, 0, 0);
      }
    }
  }

  __syncthreads();
  char* hbuf = smem + w * 9216;
  char* lbuf = hbuf + 4608;
#pragma unroll
  for (int mi = 0; mi < 2; ++mi)
#pragma unroll
    for (int nj = 0; nj < 4; ++nj)
#pragma unroll
      for (int r = 0; r < 4; ++r) {
        int row = mi * 16 + lc * 4 + r;
        int col = nj * 16 + lr;
        float v = acc[mi][nj][r] + ba[n0 + wc * 64 + col];
        unsigned hb = bf16rn(v);
        *(unsigned short*)(hbuf + row * 144 + col * 2) = (unsigned short)hb;
        if (!vsec)
          *(unsigned short*)(lbuf + row * 144 + col * 2) = (unsigned short)bf16rn(v - bf16f(hb));
      }
#pragma unroll
  for (int ps = 0; ps < 4; ++ps) {
    int rr = ps * 8 + (lane >> 3);
    int c = lane & 7;
    size_t gb = ((size_t)(m0 + wr * 32 + rr) * 3072 + n0 + wc * 64) * 2 + (c << 4);
    *(uint4*)(qhi + gb) = *(const uint4*)(hbuf + rr * 144 + c * 16);
    if (!vsec) *(uint4*)(qlo + gb) = *(const uint4*)(lbuf + rr * 144 + c * 16);
  }
}

// ---------------- fused QK^T + causal softmax -> att (bf16) + attlast ----------------
#define QSLDS 2304  // 16 rows * 144B
__global__ void __launch_bounds__(512) qk_softmax(
    const char* __restrict__ qhi, const char* __restrict__ qlo,
    char* __restrict__ attB, float* __restrict__ attlast)
{
  int rb = blockIdx.x, h = blockIdx.y;
  int i0 = rb * 32;
  bool full = (rb == 31);
  int tid = threadIdx.x, lane = tid & 63, w = tid >> 6;
  int wr = w >> 2, wcg = w & 3;
  int lr = lane & 15, lc = lane >> 4;
  __shared__ float redm[2][16][4];
  __shared__ float reds[2][16][4];
  __shared__ __align__(16) char tb[8][QSLDS];

  int iq = i0 + wr * 16 + lr;
  short8 ah[2];
  short8 al[2] = {short8{0,0,0,0,0,0,0,0}, short8{0,0,0,0,0,0,0,0}};
  {
    size_t qb = (size_t)iq * 6144 + h * 128;
#pragma unroll
    for (int kh = 0; kh < 2; ++kh)
      ah[kh] = *(const short8*)(qhi + qb + ((kh * 4 + lc) << 4));
    if (full) {
#pragma unroll
      for (int kh = 0; kh < 2; ++kh)
        al[kh] = *(const short8*)(qlo + qb + ((kh * 4 + lc) << 4));
    }
  }

  f32x4 acc[16];
#pragma unroll
  for (int nt = 0; nt < 16; ++nt) acc[nt] = (f32x4){0.f, 0.f, 0.f, 0.f};

  int maxj = i0 + 31;
#pragma unroll
  for (int nt = 0; nt < 16; ++nt) {
    if (wcg * 256 + nt * 16 <= maxj) {
      int jr = wcg * 256 + nt * 16 + lr;
      size_t kb = (size_t)jr * 6144 + 2048 + h * 128;
      short8 bh[2];
#pragma unroll
      for (int kh = 0; kh < 2; ++kh)
        bh[kh] = *(const short8*)(qhi + kb + ((kh * 4 + lc) << 4));
      if (full) {
        short8 bl[2];
#pragma unroll
        for (int kh = 0; kh < 2; ++kh)
          bl[kh] = *(const short8*)(qlo + kb + ((kh * 4 + lc) << 4));
#pragma unroll
        for (int kh = 0; kh < 2; ++kh) {
          acc[nt] = __builtin_amdgcn_mfma_f32_16x16x32_bf16(ah[kh], bh[kh], acc[nt], 0, 0, 0);
          acc[nt] = __builtin_amdgcn_mfma_f32_16x16x32_bf16(al[kh], bh[kh], acc[nt], 0, 0, 0);
          acc[nt] = __builtin_amdgcn_mfma_f32_16x16x32_bf16(ah[kh], bl[kh], acc[nt], 0, 0, 0);
        }
      } else {
#pragma unroll
        for (int kh = 0; kh < 2; ++kh)
          acc[nt] = __builtin_amdgcn_mfma_f32_16x16x32_bf16(ah[kh], bh[kh], acc[nt], 0, 0, 0);
      }
    }
  }

  int iv[4];
  float pmax[4];
#pragma unroll
  for (int r = 0; r < 4; ++r) {
    iv[r] = i0 + wr * 16 + lc * 4 + r;
    pmax[r] = -INFINITY;
  }
#pragma unroll
  for (int nt = 0; nt < 16; ++nt) {
    if (wcg * 256 + nt * 16 <= maxj) {
      int j = wcg * 256 + nt * 16 + lr;
#pragma unroll
      for (int r = 0; r < 4; ++r) {
        float v = (j <= iv[r]) ? acc[nt][r] * 0.125f : -INFINITY;
        acc[nt][r] = v;
        pmax[r] = fmaxf(pmax[r], v);
      }
    }
  }
#pragma unroll
  for (int o = 1; o <= 8; o <<= 1)
#pragma unroll
    for (int r = 0; r < 4; ++r) pmax[r] = fmaxf(pmax[r], __shfl_xor(pmax[r], o));
  if (lr == 0) {
#pragma unroll
    for (int r = 0; r < 4; ++r) redm[wr][lc * 4 + r][wcg] = pmax[r];
  }
  __syncthreads();
  float rowm[4];
#pragma unroll
  for (int r = 0; r < 4; ++r) {
    float* q = redm[wr][lc * 4 + r];
    rowm[r] = fmaxf(fmaxf(q[0], q[1]), fmaxf(q[2], q[3]));
  }

  float psum[4] = {0.f, 0.f, 0.f, 0.f};
#pragma unroll
  for (int nt = 0; nt < 16; ++nt) {
    if (wcg * 256 + nt * 16 <= maxj) {
#pragma unroll
      for (int r = 0; r < 4; ++r) {
        float e = __expf(acc[nt][r] - rowm[r]);
        acc[nt][r] = e;
        psum[r] += e;
      }
    }
  }
#pragma unroll
  for (int o = 1; o <= 8; o <<= 1)
#pragma unroll
    for (int r = 0; r < 4; ++r) psum[r] += __shfl_xor(psum[r], o);
  if (lr == 0) {
#pragma unroll
    for (int r = 0; r < 4; ++r) reds[wr][lc * 4 + r][wcg] = psum[r];
  }
  __syncthreads();
  float inv[4];
#pragma unroll
  for (int r = 0; r < 4; ++r) {
    float* q = reds[wr][lc * 4 + r];
    inv[r] = 1.0f / (q[0] + q[1] + q[2] + q[3]);
  }

  char* mybuf = tb[w];
  int iv0 = i0 + wr * 16;
  int limit128 = (i0 & ~127) + 128;
#pragma unroll
  for (int cc = 0; cc < 4; ++cc) {
    if (wcg * 256 + cc * 64 < limit128) {
#pragma unroll
      for (int q = 0; q < 4; ++q) {
        int nt = cc * 4 + q;
        int col = q * 16 + lr;
#pragma unroll
        for (int r = 0; r < 4; ++r) {
          int row = lc * 4 + r;
          float v = acc[nt][r] * inv[r];
          *(unsigned short*)(mybuf + row * 144 + col * 2) = (unsigned short)bf16rn(v);
          if (iv[r] == 1023) attlast[(h << 10) + wcg * 256 + cc * 64 + col] = v;
        }
      }
#pragma unroll
      for (int half = 0; half < 2; ++half) {
        int rr = (lane >> 3) + half * 8;
        int c = lane & 7;
        int rowg = iv0 + rr;
        uint4 hv = *(const uint4*)(mybuf + rr * 144 + c * 16);
        size_t basep = ((size_t)h << 21) + ((size_t)rowg << 11)
                     + (size_t)(((wcg << 2) + cc) << 7) + (size_t)(c << 4);
        *(uint4*)(attB + basep) = hv;
      }
    }
  }
}

// ---------------- MFMA distance + top-4 (static addressing, 2-phase; MQ=5 for 5 blocks/CU) ----------------
#define BUFB 16384

#define TOPK_STEP(PAR, DO_STAGE)                                              \
  {                                                                           \
    if (DO_STAGE) {                                                           \
      _Pragma("unroll")                                                       \
      for (int i2 = 0; i2 < 4; ++i2) {                                        \
        __builtin_amdgcn_global_load_lds(                                     \
            (const __attribute__((address_space(1))) unsigned int*)stsrc[i2], \
            (__attribute__((address_space(3))) unsigned int*)(stdst[i2] + ((PAR) ^ 16384)), \
            16, 0, 0);                                                        \
        stsrc[i2] += 8192;                                                    \
      }                                                                       \
    }                                                                         \
    f32x4 acc[4];                                                             \
    _Pragma("unroll")                                                         \
    for (int ms = 0; ms < 4; ++ms)                                            \
      acc[ms] = *(const f32x4*)(knp + ms * 64);                               \
    knp += 256;                                                               \
    _Pragma("unroll")                                                         \
    for (int ms = 0; ms < 4; ++ms) {                                          \
      short8 ah0 = *(const short8*)(frg[ms * 2 + 0] + (PAR));                 \
      short8 al0 = *(const short8*)(frg[ms * 2 + 0] + (PAR) + 8192);          \
      short8 ah1 = *(const short8*)(frg[ms * 2 + 1] + (PAR));                 \
      short8 al1 = *(const short8*)(frg[ms * 2 + 1] + (PAR) + 8192);          \
      acc[ms] = __builtin_amdgcn_mfma_f32_16x16x32_bf16(ah0, bhi[0], acc[ms], 0, 0, 0); \
      acc[ms] = __builtin_amdgcn_mfma_f32_16x16x32_bf16(al0, bhi[0], acc[ms], 0, 0, 0); \
      acc[ms] = __builtin_amdgcn_mfma_f32_16x16x32_bf16(ah0, blo[0], acc[ms], 0, 0, 0); \
      acc[ms] = __builtin_amdgcn_mfma_f32_16x16x32_bf16(ah1, bhi[1], acc[ms], 0, 0, 0); \
      acc[ms] = __builtin_amdgcn_mfma_f32_16x16x32_bf16(al1, bhi[1], acc[ms], 0, 0, 0); \
      acc[ms] = __builtin_amdgcn_mfma_f32_16x16x32_bf16(ah1, blo[1], acc[ms], 0, 0, 0); \
    }                                                                         \
    float pk[16];                                                             \
    _Pragma("unroll")                                                         \
    for (int ms = 0; ms < 4; ++ms)                                            \
      _Pragma("unroll")                                                       \
      for (int r = 0; r < 4; ++r) {                                           \
        unsigned u = __float_as_uint(acc[ms][r]);                             \
        pk[ms * 4 + r] = __uint_as_float((u & ~15u) | (unsigned)(ms * 4 + r)); \
      }                                                                       \
    float mx = pk[0];                                                         \
    _Pragma("unroll")                                                         \
    for (int c = 1; c < 16; ++c) mx = fmaxf(mx, pk[c]);                       \
    while (mx > ba[3]) {                                                      \
      unsigned pb = __float_as_uint(mx);                                      \
      int cl = pb & 15;                                                       \
      ba[3] = mx; bi_[3] = mg0 + ((cl & 12) << 2) + (cl & 3);                 \
      _Pragma("unroll")                                                       \
      for (int s = 3; s > 0; --s)                                             \
        if (ba[s] > ba[s - 1]) {                                              \
          float td = ba[s]; ba[s] = ba[s - 1]; ba[s - 1] = td;                \
          int ti = bi_[s]; bi_[s] = bi_[s - 1]; bi_[s - 1] = ti;              \
        }                                                                     \
      _Pragma("unroll")                                                       \
      for (int c2 = 0; c2 < 16; ++c2)                                         \
        if (pk[c2] == mx) pk[c2] = -3.0e38f;                                  \
      mx = pk[0];                                                             \
      _Pragma("unroll")                                                       \
      for (int c2 = 1; c2 < 16; ++c2) mx = fmaxf(mx, pk[c2]);                 \
    }                                                                         \
    mg0 += 64;                                                                \
    __syncthreads();                                                          \
  }

__global__ void __launch_bounds__(256, 5) topk_mfma(
    const char* __restrict__ qhi, const char* __restrict__ qlo,
    const char* __restrict__ khi, const char* __restrict__ klo,
    const float* __restrict__ kn2, float* __restrict__ pd, int* __restrict__ pi)
{
  int bid = blockIdx.x;
  int h = bid & 15, ttile = (bid >> 4) & 15, mq = bid >> 8;   // mq in 0..4
  int tid = threadIdx.x, lane = tid & 63, w = tid >> 6;
  int t0 = ttile * 64 + w * 16;
  int mqb = mq * MQB;                     // 0,1664,3328,4992,6656
  int nit2 = (mq == 4) ? 12 : 13;         // 24 or 26 tiles of 64
  __shared__ __align__(16) char smem[2 * BUFB];

  short8 bhi[2], blo[2];
  {
    int t = t0 + (lane & 15);
    size_t rb = (size_t)t * 6144 + 2048 + h * 128;
#pragma unroll
    for (int kh = 0; kh < 2; ++kh) {
      size_t off = rb + ((kh * 4 + (lane >> 4)) << 4);
      bhi[kh] = *(const short8*)(qhi + off);
      blo[kh] = *(const short8*)(qlo + off);
    }
  }

  const char* ghi = khi + ((size_t)h * MM + mqb) * 128;
  const char* glo = klo + ((size_t)h * MM + mqb) * 128;
  const char* knp = (const char*)(kn2 + (size_t)h * MM + mqb + ((lane >> 4) << 2));

  float ba[4] = {-3.0e38f, -3.0e38f, -3.0e38f, -3.0e38f};
  int   bi_[4] = {-1, -1, -1, -1};

  const char* stsrc[4];
  char* stdst[4];
  {
    int rr = lane >> 3;
    size_t laneoff = (size_t)rr * 128 + (((lane & 7) ^ rr) << 4);
#pragma unroll
    for (int i2 = 0; i2 < 4; ++i2) {
      int s = w * 4 + i2;
      stsrc[i2] = ((s < 8) ? (ghi + s * 1024) : (glo + (s - 8) * 1024)) + laneoff;
      stdst[i2] = smem + s * 1024;
    }
  }
  char* frg[8];
#pragma unroll
  for (int ms = 0; ms < 4; ++ms)
#pragma unroll
    for (int kh = 0; kh < 2; ++kh) {
      int mloc = ms * 16 + (lane & 15);
      int c = kh * 4 + (lane >> 4);
      frg[ms * 2 + kh] = smem + mloc * 128 + ((c ^ (mloc & 7)) << 4);
    }

#pragma unroll
  for (int i2 = 0; i2 < 4; ++i2) {
    __builtin_amdgcn_global_load_lds(
        (const __attribute__((address_space(1))) unsigned int*)stsrc[i2],
        (__attribute__((address_space(3))) unsigned int*)stdst[i2], 16, 0, 0);
    stsrc[i2] += 8192;
  }
  __syncthreads();

  int mg0 = mqb + ((lane >> 4) << 2);
  for (int it2 = 0; it2 < nit2; ++it2) {
    TOPK_STEP(0, true)
    TOPK_STEP(16384, (it2 < nit2 - 1))
  }

  float bd[4];
#pragma unroll
  for (int s = 0; s < 4; ++s) bd[s] = ba[s] * -2.0f;
#pragma unroll
  for (int st = 16; st <= 32; st <<= 1) {
    float sd[4]; int si[4];
#pragma unroll
    for (int s = 0; s < 4; ++s) {
      sd[s] = __shfl_xor(bd[s], st);
      si[s] = __shfl_xor(bi_[s], st);
    }
#pragma unroll
    for (int s = 0; s < 4; ++s) ins4(sd[s], si[s], bd, bi_);
  }
  if (lane < 16) {
    size_t o = (((size_t)mq * NH + h) * TT + (t0 + lane)) * 4;
#pragma unroll
    for (int s = 0; s < 4; ++s) { pd[o + s] = bd[s]; pi[o + s] = bi_[s]; }
  }
}

// ---------------- kNN attend: 8-lane merge of 5 partials; hi-only reads; vT single plane ----------------
__global__ void __launch_bounds__(1024) knn_attend(
    const char* __restrict__ qhi,
    const float* __restrict__ attlast,
    const float* __restrict__ pd, const int* __restrict__ pi,
    const float* __restrict__ kstore, const float* __restrict__ vstore,
    char* __restrict__ vThi)
{
  __shared__ __align__(16) unsigned short hiT[64][72];
  int tid = threadIdx.x, lane = tid & 63, w = tid >> 6;
  int h = blockIdx.x >> 4, t0 = (blockIdx.x & 15) << 6;

#pragma unroll
  for (int i = 0; i < 4; ++i) {
    int t = t0 + w * 4 + i;
    int g = (h << 10) + t;

    // merge the 5 M-part partial lists: 8-lane groups; lanes 5-7 hold sentinels
    float fd[4]; int fi[4];
    {
      int part = lane & 7;
      if (part < MQ) {
        size_t o = ((size_t)part * (NH * TT) + g) * 4;
#pragma unroll
        for (int s = 0; s < 4; ++s) { fd[s] = pd[o + s]; fi[s] = pi[o + s]; }
      } else {
#pragma unroll
        for (int s = 0; s < 4; ++s) { fd[s] = 3.0e38f; fi[s] = 0x7fffffff; }
      }
#pragma unroll
      for (int st = 1; st <= 4; st <<= 1) {
        float sd[4]; int si[4];
#pragma unroll
        for (int s = 0; s < 4; ++s) {
          sd[s] = __shfl_xor(fd[s], st);
          si[s] = __shfl_xor(fi[s], st);
        }
#pragma unroll
        for (int s = 0; s < 4; ++s) ins4(sd[s], si[s], fd, fi);
      }
    }

    size_t rbq = (size_t)t * 6144 + h * 128 + lane * 2;
    float q = bf16f(*(const unsigned short*)(qhi + rbq));
    float k = bf16f(*(const unsigned short*)(qhi + rbq + 2048));
    float v = bf16f(*(const unsigned short*)(qhi + rbq + 4096));
    float al = attlast[g];
    bool sel = al >= (1.0f / 8192.0f);

    float attf[5], vf[5];
    attf[0] = wredsum(q * k) * 0.125f;
    vf[0] = v;
#pragma unroll
    for (int s = 1; s < 5; ++s) {
      int m = fi[s - 1];
      const float* kp = kstore + ((size_t)h * MM + m) * DD;
      const float* vp = vstore + ((size_t)h * MM + m) * DD;
      attf[s] = wredsum(q * kp[lane]) * 0.125f;
      vf[s] = vp[lane];
    }
    float mx = attf[0];
#pragma unroll
    for (int s = 1; s < 5; ++s) mx = fmaxf(mx, attf[s]);
    float wgt[5], sum = 0.f;
#pragma unroll
    for (int s = 0; s < 5; ++s) { wgt[s] = __expf(attf[s] - mx); sum += wgt[s]; }
    float inv = 1.0f / sum;
    float vals = 0.f;
#pragma unroll
    for (int s = 0; s < 5; ++s) vals = fmaf(wgt[s] * inv, vf[s], vals);
    float r = 0.5f * vals + 0.5f * v;
    float vn = sel ? r : v;

    hiT[lane][t - t0] = (unsigned short)bf16rn(vn);
  }
  __syncthreads();

  if (tid < 512) {
    int r = tid >> 3, c = tid & 7;
    uint4 vv = *(const uint4*)&hiT[r][c * 8];
    char* dst = vThi + (size_t)((h << 6) + r) * 2048 + ((size_t)t0 << 1) + (c << 4);
    *(uint4*)dst = vv;
  }
}

// ---------------- att(bf16) @ vnewT(bf16) -> y (bf16, linear), 64x64 tiles, causal kb skip ----------------
__global__ void __launch_bounds__(256) gemm_attv(
    const char* __restrict__ attB, const char* __restrict__ vThi,
    char* __restrict__ Yhi)
{
  int h = blockIdx.y, m0 = blockIdx.x * 64;
  const char* aBase = attB + ((size_t)h << 21);
  int tid = threadIdx.x, lane = tid & 63, w = tid >> 6;
  int wr = w >> 1, wc = w & 1;
  __shared__ __align__(16) char smem[16384];
  char* sAhi = smem;
  char* sBhi = smem + 8192;
  f32x4 acc[2][2];
#pragma unroll
  for (int i = 0; i < 2; ++i)
#pragma unroll
    for (int j = 0; j < 2; ++j) acc[i][j] = (f32x4){0.f, 0.f, 0.f, 0.f};
  int lr = lane & 15, lc = lane >> 4;
  int kbEnd = (m0 >> 6) + 1;  // causal: att cols >= m0+64 are exact zeros
  for (int kb = 0; kb < kbEnd; ++kb) {
    if (kb) __syncthreads();
#pragma unroll
    for (int c8 = 0; c8 < 2; ++c8) {
      int r8 = w * 16 + c8 * 8;
      stage_rows8_swz(aBase + (size_t)(m0 + r8) * 2048 + (size_t)kb * 128, 2048, sAhi + r8 * 128, lane);
      stage_rows8_swz(vThi + (size_t)((h << 6) + r8) * 2048 + (size_t)kb * 128, 2048, sBhi + r8 * 128, lane);
    }
    __syncthreads();
#pragma unroll
    for (int kh = 0; kh < 2; ++kh) {
      short8 ah[2], bh[2];
#pragma unroll
      for (int f = 0; f < 2; ++f) {
        int ra = wr * 32 + f * 16 + lr;
        int ca = ((kh * 4 + lc) ^ (ra & 7)) << 4;
        ah[f] = *(const short8*)(sAhi + ra * 128 + ca);
        int rbr = wc * 32 + f * 16 + lr;
        int cb = ((kh * 4 + lc) ^ (rbr & 7)) << 4;
        bh[f] = *(const short8*)(sBhi + rbr * 128 + cb);
      }
#pragma unroll
      for (int mi = 0; mi < 2; ++mi)
#pragma unroll
        for (int nj = 0; nj < 2; ++nj)
          acc[mi][nj] = __builtin_amdgcn_mfma_f32_16x16x32_bf16(ah[mi], bh[nj], acc[mi][nj], 0, 0, 0);
    }
  }
#pragma unroll
  for (int mi = 0; mi < 2; ++mi)
#pragma unroll
    for (int nj = 0; nj < 2; ++nj)
#pragma unroll
      for (int r = 0; r < 4; ++r) {
        int m = m0 + wr * 32 + mi * 16 + lc * 4 + r;
        int n = (h << 6) + wc * 32 + nj * 16 + lr;
        size_t off = ((size_t)m * 1024 + n) * 2;
        *(unsigned short*)(Yhi + off) = (unsigned short)bf16rn(acc[mi][nj][r]);
      }
}

// ---------------- out = y(bf16) @ Wp(bf16)^T + bp (direct f32, 64x64 tiles) ----------------
__global__ void __launch_bounds__(256) gemm_out(
    const char* __restrict__ yhi,
    const char* __restrict__ wphi,
    const float* __restrict__ bp, float* __restrict__ out)
{
  int n0 = blockIdx.x * 64, m0 = blockIdx.y * 64;
  int tid = threadIdx.x, lane = tid & 63, w = tid >> 6;
  int wr = w >> 1, wc = w & 1;
  int lr = lane & 15, lc = lane >> 4;
  __shared__ __align__(16) char smem[16384];
  char* sAhi = smem;
  char* sBhi = smem + 8192;
  f32x4 acc[2][2];
#pragma unroll
  for (int i = 0; i < 2; ++i)
#pragma unroll
    for (int j = 0; j < 2; ++j) acc[i][j] = (f32x4){0.f, 0.f, 0.f, 0.f};

  for (int kb = 0; kb < 16; ++kb) {
    if (kb) __syncthreads();
#pragma unroll
    for (int c8 = 0; c8 < 2; ++c8) {
      int r8 = w * 16 + c8 * 8;
      stage_rows8_swz(yhi + (size_t)(m0 + r8) * 2048 + (size_t)kb * 128, 2048, sAhi + r8 * 128, lane);
      stage_rows8_swz(wphi + (size_t)(n0 + r8) * 2048 + (size_t)kb * 128, 2048, sBhi + r8 * 128, lane);
    }
    __syncthreads();
#pragma unroll
    for (int kh = 0; kh < 2; ++kh) {
      short8 ah[2], bh[2];
#pragma unroll
      for (int mi = 0; mi < 2; ++mi) {
        int ra = wr * 32 + mi * 16 + lr;
        int ca = ((kh * 4 + lc) ^ (ra & 7)) << 4;
        ah[mi] = *(const short8*)(sAhi + ra * 128 + ca);
      }
#pragma unroll
      for (int nj = 0; nj < 2; ++nj) {
        int rb = wc * 32 + nj * 16 + lr;
        int cb = ((kh * 4 + lc) ^ (rb & 7)) << 4;
        bh[nj] = *(const short8*)(sBhi + rb * 128 + cb);
      }
#pragma unroll
      for (int mi = 0; mi < 2; ++mi)
#pragma unroll
        for (int nj = 0; nj < 2; ++nj)
          acc[mi][nj] = __builtin_amdgcn_mfma_f32_16x16x32_bf16(ah[mi], bh[nj], acc[mi][nj], 0, 0, 0);
    }
  }
#pragma unroll
  for (int mi = 0; mi < 2; ++mi)
#pragma unroll
    for (int nj = 0; nj < 2; ++nj)
#pragma unroll
      for (int r = 0; r < 4; ++r) {
        int m = m0 + wr * 32 + mi * 16 + lc * 4 + r;
        int n = n0 + wc * 32 + nj * 16 + lr;
        out[(size_t)m * 1024 + n] = acc[mi][nj][r] + bp[n];
      }
}

// ---------------- launch ----------------
extern "C" void kernel_launch(void* const* d_in, const int* in_sizes, int n_in,
                              void* d_out, int out_size, void* d_ws, size_t ws_size,
                              hipStream_t stream) {
  (void)in_sizes; (void)n_in; (void)out_size; (void)ws_size;
  const float* x  = (const float*)d_in[0];
  const float* Wa = (const float*)d_in[1];
  const float* ba = (const float*)d_in[2];
  const float* Wp = (const float*)d_in[3];
  const float* bp = (const float*)d_in[4];
  const float* Ks = (const float*)d_in[5];
  const float* Vs = (const float*)d_in[6];
  float* out = (float*)d_out;

  char* base = (char*)d_ws;
  char* xhi  = base;
  char* xlo  = base + 0x200000;
  char* wahi = base + 0x400000;
  char* walo = base + 0xA00000;
  char* khi  = base + 0x1000000;
  char* klo  = base + 0x2000000;
  char*  attB = base;                        // att bf16 single plane (32 MB), overlays dead regions
  char* tail = base + 0x4000000;
  char* qhi = tail;
  char* qlo = tail + 0x600000;
  float* attlast = (float*)(tail + 0xC00000);
  float* kn2     = (float*)(tail + 0xC10000);
  float* pd      = (float*)(tail + 0xC90000);   // 5*16*1024*4 f32 = 1.25 MB
  int*   pi      = (int*)(tail + 0xE90000);     // 1.25 MB
  char* vThi = tail + 0x1090000;
  char* yhi  = tail + 0x1290000;
  char* wphi = tail + 0x1490000;

  // 1) fused converts
  hipLaunchKernelGGL(convert_all, dim3(6656), dim3(256), 0, stream,
                     x, xhi, xlo, Wa, wahi, walo, Wp, wphi, Ks, khi, klo, kn2);
  // 2) qkv = x @ Wa^T + ba -> qhl (v section 1-term, hi-only)
  hipLaunchKernelGGL(gemm_qkv, dim3(24, 16), dim3(256), 0, stream,
                     (const char*)xhi, (const char*)xlo, (const char*)wahi, (const char*)walo,
                     ba, qhi, qlo);
  // 3) top-4 over key store (MQ=5 uneven split -> 5 blocks/CU)
  hipLaunchKernelGGL(topk_mfma, dim3(16 * 16 * MQ), dim3(256), 0, stream,
                     (const char*)qhi, (const char*)qlo, (const char*)khi, (const char*)klo,
                     kn2, pd, pi);
  // 4) fused QK^T + causal softmax -> att bf16 + attlast
  hipLaunchKernelGGL(qk_softmax, dim3(32, 16), dim3(512), 0, stream,
                     (const char*)qhi, (const char*)qlo, attB, attlast);
  // 5) kNN attend -> v_new^T bf16 (8-lane merge of 5 partials)
  hipLaunchKernelGGL(knn_attend, dim3(256), dim3(1024), 0, stream,
                     (const char*)qhi, attlast, pd, pi, Ks, Vs, vThi);
  // 6) y = att @ v_new -> y bf16 (64x64 tiles)
  hipLaunchKernelGGL(gemm_attv, dim3(16, 16), dim3(256), 0, stream,
                     (const char*)attB, (const char*)vThi, yhi);
  // 7) out = y @ Wp^T + bp
  hipLaunchKernelGGL(gemm_out, dim3(16, 16), dim3(256), 0, stream,
                     (const char*)yhi, (const char*)wphi, bp, out);
}

// Round 24
// 195.088 us; speedup vs baseline: 1.0726x; 1.0726x over previous
//
#include <hip/hip_runtime.h>
#include <math.h>

#define NH 16
#define TT 1024
#define CC 1024
#define DD 64
#define MM 8192
#define MQ 4
#define MQS (MM / MQ)

typedef __attribute__((ext_vector_type(8))) short short8;
typedef __attribute__((ext_vector_type(4))) float f32x4;

// ---------------- helpers ----------------
__device__ __forceinline__ float wredsum(float x) {
#pragma unroll
  for (int o = 32; o; o >>= 1) x += __shfl_xor(x, o);
  return x;
}
__device__ __forceinline__ unsigned int bf16rn(float x) {
  unsigned int u = __float_as_uint(x);
  return (u + 0x7fffu + ((u >> 16) & 1u)) >> 16;
}
__device__ __forceinline__ float bf16f(unsigned int h) {
  return __uint_as_float(h << 16);
}

__device__ __forceinline__ void ins4(float d, int i, float vd[4], int vi[4]) {
  if (d < vd[3] || (d == vd[3] && i < vi[3])) {
    vd[3] = d; vi[3] = i;
#pragma unroll
    for (int s = 3; s > 0; --s) {
      bool sw = (vd[s] < vd[s - 1]) || (vd[s] == vd[s - 1] && vi[s] < vi[s - 1]);
      if (sw) {
        float td = vd[s]; vd[s] = vd[s - 1]; vd[s - 1] = td;
        int ti = vi[s]; vi[s] = vi[s - 1]; vi[s - 1] = ti;
      }
    }
  }
}

// ---------------- staging (global LINEAR -> LDS swizzled) ----------------
__device__ __forceinline__ void stage_rows8_swz(const char* gRow0, size_t gStride, char* lds, int lane) {
  int rr = lane >> 3;
  int c = (lane & 7) ^ rr;
  __builtin_amdgcn_global_load_lds(
      (const __attribute__((address_space(1))) unsigned int*)(gRow0 + (size_t)rr * gStride + (c << 4)),
      (__attribute__((address_space(3))) unsigned int*)lds, 16, 0, 0);
}

// ---------------- fused converts ----------------
__device__ __forceinline__ void conv_chunk(const float* __restrict__ src,
                                           char* __restrict__ hi, char* __restrict__ lo, int gc) {
  const float* p = src + ((size_t)gc << 3);
  float4 f0 = *(const float4*)p;
  float4 f1 = *(const float4*)(p + 4);
  float f[8] = {f0.x, f0.y, f0.z, f0.w, f1.x, f1.y, f1.z, f1.w};
  short8 hv, lv;
#pragma unroll
  for (int e = 0; e < 8; ++e) {
    unsigned hb = bf16rn(f[e]);
    hv[e] = (short)hb;
    lv[e] = (short)bf16rn(f[e] - bf16f(hb));
  }
  size_t off = (size_t)gc << 4;
  *(short8*)(hi + off) = hv;
  *(short8*)(lo + off) = lv;
}

__device__ __forceinline__ void conv_chunk_hi(const float* __restrict__ src,
                                              char* __restrict__ hi, int gc) {
  const float* p = src + ((size_t)gc << 3);
  float4 f0 = *(const float4*)p;
  float4 f1 = *(const float4*)(p + 4);
  float f[8] = {f0.x, f0.y, f0.z, f0.w, f1.x, f1.y, f1.z, f1.w};
  short8 hv;
#pragma unroll
  for (int e = 0; e < 8; ++e) hv[e] = (short)bf16rn(f[e]);
  *(short8*)(hi + ((size_t)gc << 4)) = hv;
}

__global__ void __launch_bounds__(256) convert_all(
    const float* __restrict__ x, char* __restrict__ xhi, char* __restrict__ xlo,
    const float* __restrict__ Wa, char* __restrict__ wahi, char* __restrict__ walo,
    const float* __restrict__ Wp, char* __restrict__ wphi,
    const float* __restrict__ ks, char* __restrict__ khi, char* __restrict__ klo,
    float* __restrict__ kn2)
{
  int b = blockIdx.x, tid = threadIdx.x;
  if (b < 512) { conv_chunk(x, xhi, xlo, b * 256 + tid); return; }
  if (b < 2048) {
    int gc = (b - 512) * 256 + tid;
    if (gc < 262144) conv_chunk(Wa, wahi, walo, gc);       // q,k rows: hi+lo
    else conv_chunk_hi(Wa, wahi, gc);                      // v rows: hi only
    return;
  }
  if (b < 2560) { conv_chunk_hi(Wp, wphi, (b - 2048) * 256 + tid); return; }
  int gc = (b - 2560) * 256 + tid;
  const float* p = ks + ((size_t)gc << 3);
  float4 f0 = *(const float4*)p;
  float4 f1 = *(const float4*)(p + 4);
  float f[8] = {f0.x, f0.y, f0.z, f0.w, f1.x, f1.y, f1.z, f1.w};
  float s = 0.f;
  short8 hv, lv;
#pragma unroll
  for (int e = 0; e < 8; ++e) {
    s = fmaf(f[e], f[e], s);
    unsigned hb = bf16rn(f[e]);
    hv[e] = (short)hb;
    lv[e] = (short)bf16rn(f[e] - bf16f(hb));
  }
  size_t off = (size_t)gc << 4;
  *(short8*)(khi + off) = hv;
  *(short8*)(klo + off) = lv;
  s += __shfl_xor(s, 1);
  s += __shfl_xor(s, 2);
  s += __shfl_xor(s, 4);
  if ((tid & 7) == 0) kn2[gc >> 3] = -0.5f * s;
}

// ---------------- qkv = x @ Wa^T + ba -> linear HL (direct) ----------------
__global__ void __launch_bounds__(256) gemm_qkv(
    const char* __restrict__ xhi, const char* __restrict__ xlo,
    const char* __restrict__ wahi, const char* __restrict__ walo,
    const float* __restrict__ ba, char* __restrict__ qhi, char* __restrict__ qlo)
{
  int n0 = blockIdx.x * 128, m0 = blockIdx.y * 64;
  bool vsec = (n0 >= 2048);
  int tid = threadIdx.x, lane = tid & 63, w = tid >> 6;
  int wr = w >> 1, wc = w & 1;
  int lr = lane & 15, lc = lane >> 4;
  __shared__ __align__(16) char smem[49152];
  char* sAhi = smem;
  char* sAlo = smem + 8192;
  char* sBhi = smem + 16384;
  char* sBlo = smem + 32768;
  f32x4 acc[2][4];
#pragma unroll
  for (int i = 0; i < 2; ++i)
#pragma unroll
    for (int j = 0; j < 4; ++j) acc[i][j] = (f32x4){0.f, 0.f, 0.f, 0.f};

  for (int kb = 0; kb < 16; ++kb) {
    if (kb) __syncthreads();
#pragma unroll
    for (int c8 = 0; c8 < 2; ++c8) {
      int r8 = w * 16 + c8 * 8;
      stage_rows8_swz(xhi + (size_t)(m0 + r8) * 2048 + (size_t)kb * 128, 2048, sAhi + r8 * 128, lane);
      if (!vsec)
        stage_rows8_swz(xlo + (size_t)(m0 + r8) * 2048 + (size_t)kb * 128, 2048, sAlo + r8 * 128, lane);
    }
#pragma unroll
    for (int c8 = 0; c8 < 4; ++c8) {
      int r8 = w * 32 + c8 * 8;
      stage_rows8_swz(wahi + (size_t)(n0 + r8) * 2048 + (size_t)kb * 128, 2048, sBhi + r8 * 128, lane);
      if (!vsec)
        stage_rows8_swz(walo + (size_t)(n0 + r8) * 2048 + (size_t)kb * 128, 2048, sBlo + r8 * 128, lane);
    }
    __syncthreads();
#pragma unroll
    for (int kh = 0; kh < 2; ++kh) {
      short8 ah[2], al[2], bh[4], bl[4];
#pragma unroll
      for (int mi = 0; mi < 2; ++mi) {
        int ra = wr * 32 + mi * 16 + lr;
        int ca = ((kh * 4 + lc) ^ (ra & 7)) << 4;
        ah[mi] = *(const short8*)(sAhi + ra * 128 + ca);
        if (!vsec) al[mi] = *(const short8*)(sAlo + ra * 128 + ca);
      }
#pragma unroll
      for (int nj = 0; nj < 4; ++nj) {
        int rb = wc * 64 + nj * 16 + lr;
        int cb = ((kh * 4 + lc) ^ (rb & 7)) << 4;
        bh[nj] = *(const short8*)(sBhi + rb * 128 + cb);
        if (!vsec) bl[nj] = *(const short8*)(sBlo + rb * 128 + cb);
      }
      if (!vsec) {
#pragma unroll
        for (int mi = 0; mi < 2; ++mi)
#pragma unroll
          for (int nj = 0; nj < 4; ++nj) {
            acc[mi][nj] = __builtin_amdgcn_mfma_f32_16x16x32_bf16(ah[mi], bh[nj], acc[mi][nj], 0, 0, 0);
            acc[mi][nj] = __builtin_amdgcn_mfma_f32_16x16x32_bf16(al[mi], bh[nj], acc[mi][nj], 0, 0, 0);
            acc[mi][nj] = __builtin_amdgcn_mfma_f32_16x16x32_bf16(ah[mi], bl[nj], acc[mi][nj], 0, 0, 0);
          }
      } else {
#pragma unroll
        for (int mi = 0; mi < 2; ++mi)
#pragma unroll
          for (int nj = 0; nj < 4; ++nj)
            acc[mi][nj] = __builtin_amdgcn_mfma_f32_16x16x32_bf16(ah[mi], bh[nj], acc[mi][nj], 0, 0, 0);
      }
    }
  }

  __syncthreads();
  char* hbuf = smem + w * 9216;
  char* lbuf = hbuf + 4608;
#pragma unroll
  for (int mi = 0; mi < 2; ++mi)
#pragma unroll
    for (int nj = 0; nj < 4; ++nj)
#pragma unroll
      for (int r = 0; r < 4; ++r) {
        int row = mi * 16 + lc * 4 + r;
        int col = nj * 16 + lr;
        float v = acc[mi][nj][r] + ba[n0 + wc * 64 + col];
        unsigned hb = bf16rn(v);
        *(unsigned short*)(hbuf + row * 144 + col * 2) = (unsigned short)hb;
        if (!vsec)
          *(unsigned short*)(lbuf + row * 144 + col * 2) = (unsigned short)bf16rn(v - bf16f(hb));
      }
#pragma unroll
  for (int ps = 0; ps < 4; ++ps) {
    int rr = ps * 8 + (lane >> 3);
    int c = lane & 7;
    size_t gb = ((size_t)(m0 + wr * 32 + rr) * 3072 + n0 + wc * 64) * 2 + (c << 4);
    *(uint4*)(qhi + gb) = *(const uint4*)(hbuf + rr * 144 + c * 16);
    if (!vsec) *(uint4*)(qlo + gb) = *(const uint4*)(lbuf + rr * 144 + c * 16);
  }
}

// ---------------- fused QK^T + causal softmax -> att (bf16) + attlast ----------------
#define QSLDS 2304  // 16 rows * 144B
__global__ void __launch_bounds__(512) qk_softmax(
    const char* __restrict__ qhi, const char* __restrict__ qlo,
    char* __restrict__ attB, float* __restrict__ attlast)
{
  int rb = blockIdx.x, h = blockIdx.y;
  int i0 = rb * 32;
  bool full = (rb == 31);
  int tid = threadIdx.x, lane = tid & 63, w = tid >> 6;
  int wr = w >> 2, wcg = w & 3;
  int lr = lane & 15, lc = lane >> 4;
  __shared__ float redm[2][16][4];
  __shared__ float reds[2][16][4];
  __shared__ __align__(16) char tb[8][QSLDS];

  int iq = i0 + wr * 16 + lr;
  short8 ah[2];
  short8 al[2] = {short8{0,0,0,0,0,0,0,0}, short8{0,0,0,0,0,0,0,0}};
  {
    size_t qb = (size_t)iq * 6144 + h * 128;
#pragma unroll
    for (int kh = 0; kh < 2; ++kh)
      ah[kh] = *(const short8*)(qhi + qb + ((kh * 4 + lc) << 4));
    if (full) {
#pragma unroll
      for (int kh = 0; kh < 2; ++kh)
        al[kh] = *(const short8*)(qlo + qb + ((kh * 4 + lc) << 4));
    }
  }

  f32x4 acc[16];
#pragma unroll
  for (int nt = 0; nt < 16; ++nt) acc[nt] = (f32x4){0.f, 0.f, 0.f, 0.f};

  int maxj = i0 + 31;
#pragma unroll
  for (int nt = 0; nt < 16; ++nt) {
    if (wcg * 256 + nt * 16 <= maxj) {
      int jr = wcg * 256 + nt * 16 + lr;
      size_t kb = (size_t)jr * 6144 + 2048 + h * 128;
      short8 bh[2];
#pragma unroll
      for (int kh = 0; kh < 2; ++kh)
        bh[kh] = *(const short8*)(qhi + kb + ((kh * 4 + lc) << 4));
      if (full) {
        short8 bl[2];
#pragma unroll
        for (int kh = 0; kh < 2; ++kh)
          bl[kh] = *(const short8*)(qlo + kb + ((kh * 4 + lc) << 4));
#pragma unroll
        for (int kh = 0; kh < 2; ++kh) {
          acc[nt] = __builtin_amdgcn_mfma_f32_16x16x32_bf16(ah[kh], bh[kh], acc[nt], 0, 0, 0);
          acc[nt] = __builtin_amdgcn_mfma_f32_16x16x32_bf16(al[kh], bh[kh], acc[nt], 0, 0, 0);
          acc[nt] = __builtin_amdgcn_mfma_f32_16x16x32_bf16(ah[kh], bl[kh], acc[nt], 0, 0, 0);
        }
      } else {
#pragma unroll
        for (int kh = 0; kh < 2; ++kh)
          acc[nt] = __builtin_amdgcn_mfma_f32_16x16x32_bf16(ah[kh], bh[kh], acc[nt], 0, 0, 0);
      }
    }
  }

  int iv[4];
  float pmax[4];
#pragma unroll
  for (int r = 0; r < 4; ++r) {
    iv[r] = i0 + wr * 16 + lc * 4 + r;
    pmax[r] = -INFINITY;
  }
#pragma unroll
  for (int nt = 0; nt < 16; ++nt) {
    if (wcg * 256 + nt * 16 <= maxj) {
      int j = wcg * 256 + nt * 16 + lr;
#pragma unroll
      for (int r = 0; r < 4; ++r) {
        float v = (j <= iv[r]) ? acc[nt][r] * 0.125f : -INFINITY;
        acc[nt][r] = v;
        pmax[r] = fmaxf(pmax[r], v);
      }
    }
  }
#pragma unroll
  for (int o = 1; o <= 8; o <<= 1)
#pragma unroll
    for (int r = 0; r < 4; ++r) pmax[r] = fmaxf(pmax[r], __shfl_xor(pmax[r], o));
  if (lr == 0) {
#pragma unroll
    for (int r = 0; r < 4; ++r) redm[wr][lc * 4 + r][wcg] = pmax[r];
  }
  __syncthreads();
  float rowm[4];
#pragma unroll
  for (int r = 0; r < 4; ++r) {
    float* q = redm[wr][lc * 4 + r];
    rowm[r] = fmaxf(fmaxf(q[0], q[1]), fmaxf(q[2], q[3]));
  }

  float psum[4] = {0.f, 0.f, 0.f, 0.f};
#pragma unroll
  for (int nt = 0; nt < 16; ++nt) {
    if (wcg * 256 + nt * 16 <= maxj) {
#pragma unroll
      for (int r = 0; r < 4; ++r) {
        float e = __expf(acc[nt][r] - rowm[r]);
        acc[nt][r] = e;
        psum[r] += e;
      }
    }
  }
#pragma unroll
  for (int o = 1; o <= 8; o <<= 1)
#pragma unroll
    for (int r = 0; r < 4; ++r) psum[r] += __shfl_xor(psum[r], o);
  if (lr == 0) {
#pragma unroll
    for (int r = 0; r < 4; ++r) reds[wr][lc * 4 + r][wcg] = psum[r];
  }
  __syncthreads();
  float inv[4];
#pragma unroll
  for (int r = 0; r < 4; ++r) {
    float* q = reds[wr][lc * 4 + r];
    inv[r] = 1.0f / (q[0] + q[1] + q[2] + q[3]);
  }

  char* mybuf = tb[w];
  int iv0 = i0 + wr * 16;
  int limit128 = (i0 & ~127) + 128;
#pragma unroll
  for (int cc = 0; cc < 4; ++cc) {
    if (wcg * 256 + cc * 64 < limit128) {
#pragma unroll
      for (int q = 0; q < 4; ++q) {
        int nt = cc * 4 + q;
        int col = q * 16 + lr;
#pragma unroll
        for (int r = 0; r < 4; ++r) {
          int row = lc * 4 + r;
          float v = acc[nt][r] * inv[r];
          *(unsigned short*)(mybuf + row * 144 + col * 2) = (unsigned short)bf16rn(v);
          if (iv[r] == 1023) attlast[(h << 10) + wcg * 256 + cc * 64 + col] = v;
        }
      }
#pragma unroll
      for (int half = 0; half < 2; ++half) {
        int rr = (lane >> 3) + half * 8;
        int c = lane & 7;
        int rowg = iv0 + rr;
        uint4 hv = *(const uint4*)(mybuf + rr * 144 + c * 16);
        size_t basep = ((size_t)h << 21) + ((size_t)rowg << 11)
                     + (size_t)(((wcg << 2) + cc) << 7) + (size_t)(c << 4);
        *(uint4*)(attB + basep) = hv;
      }
    }
  }
}

// ---------------- MFMA distance + top-4 (static addressing, 2-phase unroll) ----------------
#define BUFB 16384

#define TOPK_STEP(PAR, DO_STAGE)                                              \
  {                                                                           \
    if (DO_STAGE) {                                                           \
      _Pragma("unroll")                                                       \
      for (int i2 = 0; i2 < 4; ++i2) {                                        \
        __builtin_amdgcn_global_load_lds(                                     \
            (const __attribute__((address_space(1))) unsigned int*)stsrc[i2], \
            (__attribute__((address_space(3))) unsigned int*)(stdst[i2] + ((PAR) ^ 16384)), \
            16, 0, 0);                                                        \
        stsrc[i2] += 8192;                                                    \
      }                                                                       \
    }                                                                         \
    f32x4 acc[4];                                                             \
    _Pragma("unroll")                                                         \
    for (int ms = 0; ms < 4; ++ms)                                            \
      acc[ms] = *(const f32x4*)(knp + ms * 64);                               \
    knp += 256;                                                               \
    _Pragma("unroll")                                                         \
    for (int ms = 0; ms < 4; ++ms) {                                          \
      short8 ah0 = *(const short8*)(frg[ms * 2 + 0] + (PAR));                 \
      short8 al0 = *(const short8*)(frg[ms * 2 + 0] + (PAR) + 8192);          \
      short8 ah1 = *(const short8*)(frg[ms * 2 + 1] + (PAR));                 \
      short8 al1 = *(const short8*)(frg[ms * 2 + 1] + (PAR) + 8192);          \
      acc[ms] = __builtin_amdgcn_mfma_f32_16x16x32_bf16(ah0, bhi[0], acc[ms], 0, 0, 0); \
      acc[ms] = __builtin_amdgcn_mfma_f32_16x16x32_bf16(al0, bhi[0], acc[ms], 0, 0, 0); \
      acc[ms] = __builtin_amdgcn_mfma_f32_16x16x32_bf16(ah0, blo[0], acc[ms], 0, 0, 0); \
      acc[ms] = __builtin_amdgcn_mfma_f32_16x16x32_bf16(ah1, bhi[1], acc[ms], 0, 0, 0); \
      acc[ms] = __builtin_amdgcn_mfma_f32_16x16x32_bf16(al1, bhi[1], acc[ms], 0, 0, 0); \
      acc[ms] = __builtin_amdgcn_mfma_f32_16x16x32_bf16(ah1, blo[1], acc[ms], 0, 0, 0); \
    }                                                                         \
    float pk[16];                                                             \
    _Pragma("unroll")                                                         \
    for (int ms = 0; ms < 4; ++ms)                                            \
      _Pragma("unroll")                                                       \
      for (int r = 0; r < 4; ++r) {                                           \
        unsigned u = __float_as_uint(acc[ms][r]);                             \
        pk[ms * 4 + r] = __uint_as_float((u & ~15u) | (unsigned)(ms * 4 + r)); \
      }                                                                       \
    float mx = pk[0];                                                         \
    _Pragma("unroll")                                                         \
    for (int c = 1; c < 16; ++c) mx = fmaxf(mx, pk[c]);                       \
    while (mx > ba[3]) {                                                      \
      unsigned pb = __float_as_uint(mx);                                      \
      int cl = pb & 15;                                                       \
      ba[3] = mx; bi_[3] = mg0 + ((cl & 12) << 2) + (cl & 3);                 \
      _Pragma("unroll")                                                       \
      for (int s = 3; s > 0; --s)                                             \
        if (ba[s] > ba[s - 1]) {                                              \
          float td = ba[s]; ba[s] = ba[s - 1]; ba[s - 1] = td;                \
          int ti = bi_[s]; bi_[s] = bi_[s - 1]; bi_[s - 1] = ti;              \
        }                                                                     \
      _Pragma("unroll")                                                       \
      for (int c2 = 0; c2 < 16; ++c2)                                         \
        if (pk[c2] == mx) pk[c2] = -3.0e38f;                                  \
      mx = pk[0];                                                             \
      _Pragma("unroll")                                                       \
      for (int c2 = 1; c2 < 16; ++c2) mx = fmaxf(mx, pk[c2]);                 \
    }                                                                         \
    mg0 += 64;                                                                \
    __syncthreads();                                                          \
  }

__global__ void __launch_bounds__(256, 4) topk_mfma(
    const char* __restrict__ qhi, const char* __restrict__ qlo,
    const char* __restrict__ khi, const char* __restrict__ klo,
    const float* __restrict__ kn2, float* __restrict__ pd, int* __restrict__ pi)
{
  int bid = blockIdx.x;
  int h = bid & 15, ttile = (bid >> 4) & 15, mq = bid >> 8;
  int tid = threadIdx.x, lane = tid & 63, w = tid >> 6;
  int t0 = ttile * 64 + w * 16;
  __shared__ __align__(16) char smem[2 * BUFB];

  short8 bhi[2], blo[2];
  {
    int t = t0 + (lane & 15);
    size_t rb = (size_t)t * 6144 + 2048 + h * 128;
#pragma unroll
    for (int kh = 0; kh < 2; ++kh) {
      size_t off = rb + ((kh * 4 + (lane >> 4)) << 4);
      bhi[kh] = *(const short8*)(qhi + off);
      blo[kh] = *(const short8*)(qlo + off);
    }
  }

  const char* ghi = khi + ((size_t)h * MM + (size_t)mq * MQS) * 128;
  const char* glo = klo + ((size_t)h * MM + (size_t)mq * MQS) * 128;
  const char* knp = (const char*)(kn2 + (size_t)h * MM + (size_t)mq * MQS + ((lane >> 4) << 2));

  float ba[4] = {-3.0e38f, -3.0e38f, -3.0e38f, -3.0e38f};
  int   bi_[4] = {-1, -1, -1, -1};

  const char* stsrc[4];
  char* stdst[4];
  {
    int rr = lane >> 3;
    size_t laneoff = (size_t)rr * 128 + (((lane & 7) ^ rr) << 4);
#pragma unroll
    for (int i2 = 0; i2 < 4; ++i2) {
      int s = w * 4 + i2;
      stsrc[i2] = ((s < 8) ? (ghi + s * 1024) : (glo + (s - 8) * 1024)) + laneoff;
      stdst[i2] = smem + s * 1024;
    }
  }
  char* frg[8];
#pragma unroll
  for (int ms = 0; ms < 4; ++ms)
#pragma unroll
    for (int kh = 0; kh < 2; ++kh) {
      int mloc = ms * 16 + (lane & 15);
      int c = kh * 4 + (lane >> 4);
      frg[ms * 2 + kh] = smem + mloc * 128 + ((c ^ (mloc & 7)) << 4);
    }

#pragma unroll
  for (int i2 = 0; i2 < 4; ++i2) {
    __builtin_amdgcn_global_load_lds(
        (const __attribute__((address_space(1))) unsigned int*)stsrc[i2],
        (__attribute__((address_space(3))) unsigned int*)stdst[i2], 16, 0, 0);
    stsrc[i2] += 8192;
  }
  __syncthreads();

  int mg0 = mq * MQS + ((lane >> 4) << 2);
  for (int it2 = 0; it2 < 16; ++it2) {
    TOPK_STEP(0, true)
    TOPK_STEP(16384, (it2 < 15))
  }

  float bd[4];
#pragma unroll
  for (int s = 0; s < 4; ++s) bd[s] = ba[s] * -2.0f;
#pragma unroll
  for (int st = 16; st <= 32; st <<= 1) {
    float sd[4]; int si[4];
#pragma unroll
    for (int s = 0; s < 4; ++s) {
      sd[s] = __shfl_xor(bd[s], st);
      si[s] = __shfl_xor(bi_[s], st);
    }
#pragma unroll
    for (int s = 0; s < 4; ++s) ins4(sd[s], si[s], bd, bi_);
  }
  if (lane < 16) {
    size_t o = (((size_t)mq * NH + h) * TT + (t0 + lane)) * 4;
#pragma unroll
    for (int s = 0; s < 4; ++s) { pd[o + s] = bd[s]; pi[o + s] = bi_[s]; }
  }
}

// ---------------- kNN attend: 1024-thr block = (h, 64 t's); hi-only reads; vT single plane ----------------
__global__ void __launch_bounds__(1024) knn_attend(
    const char* __restrict__ qhi,
    const float* __restrict__ attlast,
    const float* __restrict__ pd, const int* __restrict__ pi,
    const float* __restrict__ kstore, const float* __restrict__ vstore,
    char* __restrict__ vThi)
{
  __shared__ __align__(16) unsigned short hiT[64][72];
  int tid = threadIdx.x, lane = tid & 63, w = tid >> 6;
  int h = blockIdx.x >> 4, t0 = (blockIdx.x & 15) << 6;

#pragma unroll
  for (int i = 0; i < 4; ++i) {
    int t = t0 + w * 4 + i;
    int g = (h << 10) + t;

    float fd[4]; int fi[4];
    {
      size_t o = ((size_t)(lane & 3) * (NH * TT) + g) * 4;
#pragma unroll
      for (int s = 0; s < 4; ++s) { fd[s] = pd[o + s]; fi[s] = pi[o + s]; }
#pragma unroll
      for (int st = 1; st <= 2; st <<= 1) {
        float sd[4]; int si[4];
#pragma unroll
        for (int s = 0; s < 4; ++s) {
          sd[s] = __shfl_xor(fd[s], st);
          si[s] = __shfl_xor(fi[s], st);
        }
#pragma unroll
        for (int s = 0; s < 4; ++s) ins4(sd[s], si[s], fd, fi);
      }
    }

    size_t rbq = (size_t)t * 6144 + h * 128 + lane * 2;
    float q = bf16f(*(const unsigned short*)(qhi + rbq));
    float k = bf16f(*(const unsigned short*)(qhi + rbq + 2048));
    float v = bf16f(*(const unsigned short*)(qhi + rbq + 4096));
    float al = attlast[g];
    bool sel = al >= (1.0f / 8192.0f);

    float attf[5], vf[5];
    attf[0] = wredsum(q * k) * 0.125f;
    vf[0] = v;
#pragma unroll
    for (int s = 1; s < 5; ++s) {
      int m = fi[s - 1];
      const float* kp = kstore + ((size_t)h * MM + m) * DD;
      const float* vp = vstore + ((size_t)h * MM + m) * DD;
      attf[s] = wredsum(q * kp[lane]) * 0.125f;
      vf[s] = vp[lane];
    }
    float mx = attf[0];
#pragma unroll
    for (int s = 1; s < 5; ++s) mx = fmaxf(mx, attf[s]);
    float wgt[5], sum = 0.f;
#pragma unroll
    for (int s = 0; s < 5; ++s) { wgt[s] = __expf(attf[s] - mx); sum += wgt[s]; }
    float inv = 1.0f / sum;
    float vals = 0.f;
#pragma unroll
    for (int s = 0; s < 5; ++s) vals = fmaf(wgt[s] * inv, vf[s], vals);
    float r = 0.5f * vals + 0.5f * v;
    float vn = sel ? r : v;

    hiT[lane][t - t0] = (unsigned short)bf16rn(vn);
  }
  __syncthreads();

  if (tid < 512) {
    int r = tid >> 3, c = tid & 7;
    uint4 vv = *(const uint4*)&hiT[r][c * 8];
    char* dst = vThi + (size_t)((h << 6) + r) * 2048 + ((size_t)t0 << 1) + (c << 4);
    *(uint4*)dst = vv;
  }
}

// ---------------- att(bf16) @ vnewT(bf16) -> y (bf16, linear), 64x64 tiles, causal kb skip ----------------
__global__ void __launch_bounds__(256) gemm_attv(
    const char* __restrict__ attB, const char* __restrict__ vThi,
    char* __restrict__ Yhi)
{
  int h = blockIdx.y, m0 = blockIdx.x * 64;
  const char* aBase = attB + ((size_t)h << 21);
  int tid = threadIdx.x, lane = tid & 63, w = tid >> 6;
  int wr = w >> 1, wc = w & 1;
  __shared__ __align__(16) char smem[16384];
  char* sAhi = smem;
  char* sBhi = smem + 8192;
  f32x4 acc[2][2];
#pragma unroll
  for (int i = 0; i < 2; ++i)
#pragma unroll
    for (int j = 0; j < 2; ++j) acc[i][j] = (f32x4){0.f, 0.f, 0.f, 0.f};
  int lr = lane & 15, lc = lane >> 4;
  int kbEnd = (m0 >> 6) + 1;  // causal: att cols >= m0+64 are exact zeros
  for (int kb = 0; kb < kbEnd; ++kb) {
    if (kb) __syncthreads();
#pragma unroll
    for (int c8 = 0; c8 < 2; ++c8) {
      int r8 = w * 16 + c8 * 8;
      stage_rows8_swz(aBase + (size_t)(m0 + r8) * 2048 + (size_t)kb * 128, 2048, sAhi + r8 * 128, lane);
      stage_rows8_swz(vThi + (size_t)((h << 6) + r8) * 2048 + (size_t)kb * 128, 2048, sBhi + r8 * 128, lane);
    }
    __syncthreads();
#pragma unroll
    for (int kh = 0; kh < 2; ++kh) {
      short8 ah[2], bh[2];
#pragma unroll
      for (int f = 0; f < 2; ++f) {
        int ra = wr * 32 + f * 16 + lr;
        int ca = ((kh * 4 + lc) ^ (ra & 7)) << 4;
        ah[f] = *(const short8*)(sAhi + ra * 128 + ca);
        int rbr = wc * 32 + f * 16 + lr;
        int cb = ((kh * 4 + lc) ^ (rbr & 7)) << 4;
        bh[f] = *(const short8*)(sBhi + rbr * 128 + cb);
      }
#pragma unroll
      for (int mi = 0; mi < 2; ++mi)
#pragma unroll
        for (int nj = 0; nj < 2; ++nj)
          acc[mi][nj] = __builtin_amdgcn_mfma_f32_16x16x32_bf16(ah[mi], bh[nj], acc[mi][nj], 0, 0, 0);
    }
  }
#pragma unroll
  for (int mi = 0; mi < 2; ++mi)
#pragma unroll
    for (int nj = 0; nj < 2; ++nj)
#pragma unroll
      for (int r = 0; r < 4; ++r) {
        int m = m0 + wr * 32 + mi * 16 + lc * 4 + r;
        int n = (h << 6) + wc * 32 + nj * 16 + lr;
        size_t off = ((size_t)m * 1024 + n) * 2;
        *(unsigned short*)(Yhi + off) = (unsigned short)bf16rn(acc[mi][nj][r]);
      }
}

// ---------------- out = y(bf16) @ Wp(bf16)^T + bp (direct f32, 64x64 tiles) ----------------
__global__ void __launch_bounds__(256) gemm_out(
    const char* __restrict__ yhi,
    const char* __restrict__ wphi,
    const float* __restrict__ bp, float* __restrict__ out)
{
  int n0 = blockIdx.x * 64, m0 = blockIdx.y * 64;
  int tid = threadIdx.x, lane = tid & 63, w = tid >> 6;
  int wr = w >> 1, wc = w & 1;
  int lr = lane & 15, lc = lane >> 4;
  __shared__ __align__(16) char smem[16384];
  char* sAhi = smem;
  char* sBhi = smem + 8192;
  f32x4 acc[2][2];
#pragma unroll
  for (int i = 0; i < 2; ++i)
#pragma unroll
    for (int j = 0; j < 2; ++j) acc[i][j] = (f32x4){0.f, 0.f, 0.f, 0.f};

  for (int kb = 0; kb < 16; ++kb) {
    if (kb) __syncthreads();
#pragma unroll
    for (int c8 = 0; c8 < 2; ++c8) {
      int r8 = w * 16 + c8 * 8;
      stage_rows8_swz(yhi + (size_t)(m0 + r8) * 2048 + (size_t)kb * 128, 2048, sAhi + r8 * 128, lane);
      stage_rows8_swz(wphi + (size_t)(n0 + r8) * 2048 + (size_t)kb * 128, 2048, sBhi + r8 * 128, lane);
    }
    __syncthreads();
#pragma unroll
    for (int kh = 0; kh < 2; ++kh) {
      short8 ah[2], bh[2];
#pragma unroll
      for (int mi = 0; mi < 2; ++mi) {
        int ra = wr * 32 + mi * 16 + lr;
        int ca = ((kh * 4 + lc) ^ (ra & 7)) << 4;
        ah[mi] = *(const short8*)(sAhi + ra * 128 + ca);
      }
#pragma unroll
      for (int nj = 0; nj < 2; ++nj) {
        int rb = wc * 32 + nj * 16 + lr;
        int cb = ((kh * 4 + lc) ^ (rb & 7)) << 4;
        bh[nj] = *(const short8*)(sBhi + rb * 128 + cb);
      }
#pragma unroll
      for (int mi = 0; mi < 2; ++mi)
#pragma unroll
        for (int nj = 0; nj < 2; ++nj)
          acc[mi][nj] = __builtin_amdgcn_mfma_f32_16x16x32_bf16(ah[mi], bh[nj], acc[mi][nj], 0, 0, 0);
    }
  }
#pragma unroll
  for (int mi = 0; mi < 2; ++mi)
#pragma unroll
    for (int nj = 0; nj < 2; ++nj)
#pragma unroll
      for (int r = 0; r < 4; ++r) {
        int m = m0 + wr * 32 + mi * 16 + lc * 4 + r;
        int n = n0 + wc * 32 + nj * 16 + lr;
        out[(size_t)m * 1024 + n] = acc[mi][nj][r] + bp[n];
      }
}

// ---------------- launch ----------------
extern "C" void kernel_launch(void* const* d_in, const int* in_sizes, int n_in,
                              void* d_out, int out_size, void* d_ws, size_t ws_size,
                              hipStream_t stream) {
  (void)in_sizes; (void)n_in; (void)out_size; (void)ws_size;
  const float* x  = (const float*)d_in[0];
  const float* Wa = (const float*)d_in[1];
  const float* ba = (const float*)d_in[2];
  const float* Wp = (const float*)d_in[3];
  const float* bp = (const float*)d_in[4];
  const float* Ks = (const float*)d_in[5];
  const float* Vs = (const float*)d_in[6];
  float* out = (float*)d_out;

  char* base = (char*)d_ws;
  char* xhi  = base;
  char* xlo  = base + 0x200000;
  char* wahi = base + 0x400000;
  char* walo = base + 0xA00000;
  char* khi  = base + 0x1000000;
  char* klo  = base + 0x2000000;
  char*  attB = base;                        // att bf16 single plane (32 MB), overlays dead regions
  char* tail = base + 0x4000000;
  char* qhi = tail;
  char* qlo = tail + 0x600000;
  float* attlast = (float*)(tail + 0xC00000);
  float* kn2     = (float*)(tail + 0xC10000);
  float* pd      = (float*)(tail + 0xC90000);
  int*   pi      = (int*)(tail + 0xE90000);
  char* vThi = tail + 0x1090000;
  char* yhi  = tail + 0x1290000;
  char* wphi = tail + 0x1490000;

  // 1) fused converts
  hipLaunchKernelGGL(convert_all, dim3(6656), dim3(256), 0, stream,
                     x, xhi, xlo, Wa, wahi, walo, Wp, wphi, Ks, khi, klo, kn2);
  // 2) qkv = x @ Wa^T + ba -> qhl (v section 1-term, hi-only)
  hipLaunchKernelGGL(gemm_qkv, dim3(24, 16), dim3(256), 0, stream,
                     (const char*)xhi, (const char*)xlo, (const char*)wahi, (const char*)walo,
                     ba, qhi, qlo);
  // 3) top-4 over key store
  hipLaunchKernelGGL(topk_mfma, dim3(16 * 16 * MQ), dim3(256), 0, stream,
                     (const char*)qhi, (const char*)qlo, (const char*)khi, (const char*)klo,
                     kn2, pd, pi);
  // 4) fused QK^T + causal softmax -> att bf16 + attlast
  hipLaunchKernelGGL(qk_softmax, dim3(32, 16), dim3(512), 0, stream,
                     (const char*)qhi, (const char*)qlo, attB, attlast);
  // 5) kNN attend -> v_new^T bf16
  hipLaunchKernelGGL(knn_attend, dim3(256), dim3(1024), 0, stream,
                     (const char*)qhi, attlast, pd, pi, Ks, Vs, vThi);
  // 6) y = att @ v_new -> y bf16 (64x64 tiles)
  hipLaunchKernelGGL(gemm_attv, dim3(16, 16), dim3(256), 0, stream,
                     (const char*)attB, (const char*)vThi, yhi);
  // 7) out = y @ Wp^T + bp
  hipLaunchKernelGGL(gemm_out, dim3(16, 16), dim3(256), 0, stream,
                     (const char*)yhi, (const char*)wphi, bp, out);
}